// Round 11
// baseline (290.576 us; speedup 1.0000x reference)
//
#include <hip/hip_runtime.h>
#include <hip/hip_bf16.h>

#define EPSV 1e-5f

typedef unsigned short u16;
typedef __attribute__((ext_vector_type(8))) short short8;
typedef __attribute__((ext_vector_type(4))) float f32x4;
typedef __hip_bfloat16 bf16;

__device__ __forceinline__ unsigned int pack2(float a, float b) {
  bf16 ha = __float2bfloat16(a), hb = __float2bfloat16(b);
  u16 ua, ub;
  __builtin_memcpy(&ua, &ha, 2);
  __builtin_memcpy(&ub, &hb, 2);
  return (unsigned int)ua | ((unsigned int)ub << 16);
}

// async global->LDS, 16B per lane; LDS dest = wave-uniform base + lane*16
typedef __attribute__((address_space(1))) const void gvoid_t;
typedef __attribute__((address_space(3))) void lvoid_t;
__device__ __forceinline__ void gload16(const void* g, void* l) {
  __builtin_amdgcn_global_load_lds((gvoid_t*)g, (lvoid_t*)l, 16, 0, 0);
}

// ============================================================================
// FAST PATH (MFMA) — position-major intermediates [M=6272, C]
// ============================================================================

// ---- prep: fused attn layer-1 (blocks 0..1023) + lut transpose (1024..1791)
//      + acc zeroing (block 1792; stream-ordered before all gemm atomics)
__global__ __launch_bounds__(256) void prep_kernel(
    const float* __restrict__ x, const float* __restrict__ cent,
    const float* __restrict__ invt, u16* __restrict__ attn,
    const float* __restrict__ s1, bf16* __restrict__ d1,
    const float* __restrict__ s2, bf16* __restrict__ d2,
    const float* __restrict__ s3, bf16* __restrict__ d3,
    float* __restrict__ accz)
{
  __shared__ __align__(16) float sh[7012];   // attn1: 6468+544; lutT: 64*65=4160
  const int tid = threadIdx.x;
  if (blockIdx.x == 1792) {                  // zero acc1+acc2+acc3 (3072 f)
    for (int i = tid; i < 3072; i += 256) accz[i] = 0.f;
    return;
  }
  if (blockIdx.x >= 1024) {
    // ---------------- lutT part ----------------
    const int bid = blockIdx.x - 1024;
    const int which = bid >> 8, sub = bid & 255;
    const float* in = (which == 0) ? s1 : (which == 1) ? s2 : s3;
    bf16* out = (which == 0) ? d1 : (which == 1) ? d2 : d3;
    const int K = (which == 2) ? 1024 : 4096;
    const int N = (which == 2) ? 1024 : 256;
    const int kt = K >> 6;
    const int bk = sub & (kt - 1), bn = sub / kt;
    const int k0 = bk * 64, n0 = bn * 64;
    float* t = sh;                           // [64][65]
    for (int idx = tid; idx < 4096; idx += 256) {
      int r = idx >> 6, c = idx & 63;
      t[r * 65 + c] = in[(size_t)(k0 + r) * N + n0 + c];
    }
    __syncthreads();
    for (int idx = tid; idx < 4096; idx += 256) {
      int r = idx >> 6, c = idx & 63;
      out[(size_t)(n0 + r) * K + k0 + c] = __float2bfloat16(t[c * 65 + r]);
    }
    return;
  }
  // ---------------- attn1 part ----------------
  float* vs = sh;                            // [196][33] position-major
  float* cs = sh + 6468;                     // [8][68]
  const int bi = blockIdx.x >> 5, cg = blockIdx.x & 31;   // image, 8-cb group
  const float* xb = x + ((size_t)bi * 1024 + cg * 32) * 196;
  for (int e = tid; e < 3136; e += 256) {    // 32 ch x 98 float2
    int c = e / 98, p2 = e - c * 98;
    float2 w = *(const float2*)&xb[(size_t)c * 196 + p2 * 2];
    vs[(p2 * 2) * 33 + c] = w.x;
    vs[(p2 * 2 + 1) * 33 + c] = w.y;
  }
  if (tid < 128) {
    int cb = tid >> 4, kk = tid & 15;
    *(float4*)&cs[cb * 68 + kk * 4] =
        *(const float4*)&cent[(size_t)(cg * 8 + cb) * 64 + kk * 4];
  }
  __syncthreads();
  const float it = invt[0];
  const int cbL = tid & 7, pj = tid >> 3;    // codebook lane, 32 position slots
  float4 cv[16]; float cn[16];
  #pragma unroll
  for (int k = 0; k < 16; k++) {
    cv[k] = *(const float4*)&cs[cbL * 68 + k * 4];
    cn[k] = cv[k].x * cv[k].x + cv[k].y * cv[k].y + cv[k].z * cv[k].z + cv[k].w * cv[k].w;
  }
  for (int p = pj; p < 196; p += 32) {
    const float* vp = &vs[p * 33 + cbL * 4];
    const float v0 = vp[0], v1 = vp[1], v2 = vp[2], v3 = vp[3];
    float s[16], mx = -3e38f;
    #pragma unroll
    for (int k = 0; k < 16; k++) {
      float d = v0 * cv[k].x + v1 * cv[k].y + v2 * cv[k].z + v3 * cv[k].w;
      s[k] = it * (2.f * d - cn[k]);
      mx = fmaxf(mx, s[k]);
    }
    float sum = 0.f;
    #pragma unroll
    for (int k = 0; k < 16; k++) { float e = __expf(s[k] - mx); s[k] = e; sum += e; }
    const float r = 1.f / sum;
    uint4 w0, w1;
    w0.x = pack2(s[0] * r,  s[1] * r);  w0.y = pack2(s[2] * r,  s[3] * r);
    w0.z = pack2(s[4] * r,  s[5] * r);  w0.w = pack2(s[6] * r,  s[7] * r);
    w1.x = pack2(s[8] * r,  s[9] * r);  w1.y = pack2(s[10] * r, s[11] * r);
    w1.z = pack2(s[12] * r, s[13] * r); w1.w = pack2(s[14] * r, s[15] * r);
    uint4* dst = (uint4*)(attn + (size_t)(bi * 196 + p) * 4096 + (cg * 8 + cbL) * 16);
    dst[0] = w0; dst[1] = w1;
  }
}

// ---- attn layer 2 (3x3) v4: block = full image x 16-cb group; grid 512 ----
__global__ __launch_bounds__(256) void attn2_kernel(const float* __restrict__ out1,
    const float* __restrict__ g, const float* __restrict__ bb,
    const float* __restrict__ Sacc, const float* __restrict__ cent,
    const float* __restrict__ invt, u16* __restrict__ attn)
{
  __shared__ float vs[16 * 16 * 16];            // 16 KB [ry][rx][ch], ring = 0
  __shared__ __align__(16) float cs[16 * 196];  // 12.25 KB [cb][k*12+j] (2*it*c)
  __shared__ float cnl[16 * 17];                // it*||c||^2
  __shared__ float ssl[32];                     // [0..15]=scale, [16..31]=shift
  const int tid = threadIdx.x;
  const int bi = blockIdx.x >> 4, cg = blockIdx.x & 15;
  const float it = invt[0];
  if (tid < 16) {
    const int ch = cg * 16 + tid;
    float S = Sacc[ch], S2 = Sacc[256 + ch];
    float mean = S * (1.f / 6272.f);
    float var = S2 * (1.f / 6272.f) - mean * mean;
    float sc = g[ch] * rsqrtf(var + EPSV);
    ssl[tid] = sc; ssl[16 + tid] = bb[ch] - mean * sc;
  }
  for (int e = tid; e < 4096; e += 256) vs[e] = 0.f;
  const float it2 = 2.f * it;
  for (int idx = tid; idx < 576; idx += 256) {
    int cb = idx / 36, f4i = idx - cb * 36;
    float4 w = *(const float4*)&cent[(size_t)(cg * 16 + cb) * 144 + f4i * 4];
    int j0 = f4i * 4;
    #pragma unroll
    for (int t = 0; t < 4; t++) {
      int j = j0 + t, k = j / 9, jj = j - k * 9;
      cs[cb * 196 + k * 12 + jj] = it2 * ((const float*)&w)[t];
    }
  }
  {
    int cb = tid >> 4, k = tid & 15;
    const float* cc = &cent[(size_t)(cg * 16 + cb) * 144 + k * 9];
    float cn = 0.f;
    #pragma unroll
    for (int j = 0; j < 9; j++) cn = fmaf(cc[j], cc[j], cn);
    cnl[cb * 17 + k] = it * cn;
  }
  __syncthreads();                              // ring zero + ssl complete
  for (int e = tid; e < 784; e += 256) {
    int p = e >> 2, c4 = e & 3;
    int r = p / 14, xc = p - r * 14;
    float4 w = *(const float4*)&out1[(size_t)(bi * 196 + p) * 256 + cg * 16 + c4 * 4];
    float* dst = &vs[((r + 1) * 16 + (xc + 1)) * 16 + c4 * 4];
    dst[0] = fmaxf(w.x * ssl[c4 * 4 + 0] + ssl[16 + c4 * 4 + 0], 0.f);
    dst[1] = fmaxf(w.y * ssl[c4 * 4 + 1] + ssl[16 + c4 * 4 + 1], 0.f);
    dst[2] = fmaxf(w.z * ssl[c4 * 4 + 2] + ssl[16 + c4 * 4 + 2], 0.f);
    dst[3] = fmaxf(w.w * ssl[c4 * 4 + 3] + ssl[16 + c4 * 4 + 3], 0.f);
  }
  __syncthreads();
  const int cb = tid & 15, pj = tid >> 4;       // codebook lane, 16 pos slots
  for (int i0 = 0; i0 < 13; i0 += 2) {
    const int p0 = pj + (i0 << 4);
    const int p1 = pj + ((i0 + 1) << 4);
    const int np = (p1 < 196) ? 2 : ((p0 < 196) ? 1 : 0);
    if (np == 0) break;
    float v[2][9];
    #pragma unroll
    for (int i = 0; i < 2; i++) if (i < np) {
      const int p = i ? p1 : p0;
      const int r = p / 14, xc = p - r * 14;
      #pragma unroll
      for (int dy = 0; dy < 3; dy++)
        #pragma unroll
        for (int dx = 0; dx < 3; dx++)
          v[i][dy * 3 + dx] = vs[((r + dy) * 16 + xc + dx) * 16 + cb];
    }
    float s[2][16];
    #pragma unroll
    for (int k = 0; k < 16; k++) {
      const float* ck = &cs[cb * 196 + k * 12];
      const float4 ca = *(const float4*)ck;
      const float4 cbv = *(const float4*)(ck + 4);
      const float c8 = ck[8];
      const float cnv = cnl[cb * 17 + k];
      float c9[9] = {ca.x, ca.y, ca.z, ca.w, cbv.x, cbv.y, cbv.z, cbv.w, c8};
      #pragma unroll
      for (int i = 0; i < 2; i++) if (i < np) {
        float d = -cnv;
        #pragma unroll
        for (int j = 0; j < 9; j++) d = fmaf(c9[j], v[i][j], d);
        s[i][k] = d;
      }
    }
    #pragma unroll
    for (int i = 0; i < 2; i++) if (i < np) {
      const int p = i ? p1 : p0;
      float mx = -3e38f;
      #pragma unroll
      for (int k = 0; k < 16; k++) mx = fmaxf(mx, s[i][k]);
      float sum = 0.f;
      #pragma unroll
      for (int k = 0; k < 16; k++) { float e = __expf(s[i][k] - mx); s[i][k] = e; sum += e; }
      const float r = 1.f / sum;
      uint4 w0, w1;
      w0.x = pack2(s[i][0] * r,  s[i][1] * r);  w0.y = pack2(s[i][2] * r,  s[i][3] * r);
      w0.z = pack2(s[i][4] * r,  s[i][5] * r);  w0.w = pack2(s[i][6] * r,  s[i][7] * r);
      w1.x = pack2(s[i][8] * r,  s[i][9] * r);  w1.y = pack2(s[i][10] * r, s[i][11] * r);
      w1.z = pack2(s[i][12] * r, s[i][13] * r); w1.w = pack2(s[i][14] * r, s[i][15] * r);
      uint4* dst = (uint4*)(attn + (size_t)(bi * 196 + p) * 4096 + (cg * 16 + cb) * 16);
      dst[0] = w0; dst[1] = w1;
    }
  }
}

// ---- attn layer 3: BN2 computed inline from atomic S/S2 ----
__global__ __launch_bounds__(256) void attn3_kernel(const float* __restrict__ out2,
    const float* __restrict__ g, const float* __restrict__ bb,
    const float* __restrict__ Sacc, const float* __restrict__ cent,
    const float* __restrict__ invt, bf16* __restrict__ attn)
{
  __shared__ float ssl[512];                 // [0..255]=scale, [256..511]=shift
  const int t = threadIdx.x;
  {
    float S = Sacc[t], S2 = Sacc[256 + t];
    float mean = S * (1.f / 6272.f);
    float var = S2 * (1.f / 6272.f) - mean * mean;
    float sc = g[t] * rsqrtf(var + EPSV);
    ssl[t] = sc; ssl[256 + t] = bb[t] - mean * sc;
  }
  __syncthreads();
  const int cb = t & 63, ml = t >> 6;
  const int m0 = blockIdx.x * 16;
  const float it = invt[0];
  float4 cv[16]; float cn[16];
  const float4* cc = (const float4*)(cent + cb * 64);
  #pragma unroll
  for (int k = 0; k < 16; k++) {
    cv[k] = cc[k];
    cn[k] = cv[k].x * cv[k].x + cv[k].y * cv[k].y + cv[k].z * cv[k].z + cv[k].w * cv[k].w;
  }
  const float4 scv = *(const float4*)(ssl + cb * 4);
  const float4 shv = *(const float4*)(ssl + 256 + cb * 4);
  for (int gi = 0; gi < 4; gi++) {
    const int m = m0 + gi * 4 + ml;
    float4 xv = *(const float4*)(out2 + (size_t)m * 256 + cb * 4);
    float4 v;
    v.x = fmaxf(xv.x * scv.x + shv.x, 0.f);
    v.y = fmaxf(xv.y * scv.y + shv.y, 0.f);
    v.z = fmaxf(xv.z * scv.z + shv.z, 0.f);
    v.w = fmaxf(xv.w * scv.w + shv.w, 0.f);
    float s[16], mx = -3e38f;
    #pragma unroll
    for (int k = 0; k < 16; k++) {
      float d = v.x * cv[k].x + v.y * cv[k].y + v.z * cv[k].z + v.w * cv[k].w;
      s[k] = it * (2.f * d - cn[k]);
      mx = fmaxf(mx, s[k]);
    }
    float sum = 0.f;
    #pragma unroll
    for (int k = 0; k < 16; k++) { float e = __expf(s[k] - mx); s[k] = e; sum += e; }
    float r = 1.f / sum;
    #pragma unroll
    for (int k = 0; k < 16; k++)
      attn[(size_t)m * 1024 + cb * 16 + k] = __float2bfloat16(s[k] * r);
  }
}

// ---- bf16 MFMA GEMM: BM x BN tile, BK=64, 8 waves (4m x 2n, 512 thr),
//      KSLICES=1 always (no split-K): dbuf global_load_lds(16B), bijective
//      XCD swizzle, FUSED per-column BN-stats epilogue (atomicAdd into acc,
//      zeroed upstream in prep). Layers 1/2: BN=64 (grid 49*4=196);
//      layer 3: BN=128 (grid 49*8=392).
template<int KDIM, int NDIM, int BM, int BN, int BK>
__global__ __launch_bounds__(512) void gemm_kernel(const u16* __restrict__ A,
    const u16* __restrict__ Bt, float* __restrict__ C, float* __restrict__ stats)
{
  constexpr int NTL = NDIM / BN;
  constexpr int MT = 6272 / BM;
  constexpr int FM = BM / 64;          // wave m-frags (wave tile BM/4 x BN/2)
  constexpr int FN = BN / 32;          // wave n-frags
  constexpr int KU = BK / 32;
  constexpr int SLOTS = BK / 8;        // 16B slots per LDS row
  constexpr int RPC = 64 / SLOTS;      // rows covered per gload16 call (8)
  constexpr int ACALLS = BM / (RPC * 8);
  constexpr int BCALLS = BN / (RPC * 8) ? BN / (RPC * 8) : 1;  // >=1
  constexpr int BROWS_PER_WAVE = BN / 8;   // rows of B staged per wave (with BCALLS calls)
  __shared__ __align__(16) u16 Asm[2][BM * BK];
  __shared__ __align__(16) u16 Bsm[2][BN * BK];
  const int tid = threadIdx.x;
  // bijective XCD swizzle (m204): works for nwg % 8 != 0 (196) and == 0 (392)
  const int nwg = MT * NTL;
  const int xcd = blockIdx.x & 7, base = blockIdx.x >> 3;
  const int q = nwg >> 3, r = nwg & 7;
  const int wg = (xcd < r ? xcd * (q + 1) : r * (q + 1) + (xcd - r) * q) + base;
  const int nt = wg % NTL;
  const int mt = wg / NTL;
  const int m0 = mt * BM, n0 = nt * BN;
  const int lane = tid & 63, wid = tid >> 6;   // 8 waves
  const int wm = wid >> 1, wn = wid & 1;       // 4m x 2n
  const int lr = lane / SLOTS, sslot = lane % SLOTS;
  const int gs = sslot ^ (lr & 7);     // inverse-swizzled source slot

  f32x4 acc[FM][FN];
  #pragma unroll
  for (int i = 0; i < FM; i++)
    #pragma unroll
    for (int j = 0; j < FN; j++) acc[i][j] = (f32x4){0.f, 0.f, 0.f, 0.f};

  const u16* Abase = A + (size_t)m0 * KDIM;
  const u16* Bbase = Bt + (size_t)n0 * KDIM;

  auto stage = [&](int bf, int kb) {
    #pragma unroll
    for (int c = 0; c < ACALLS; c++) {
      const int r0 = (wid * ACALLS + c) * RPC;
      gload16(Abase + (size_t)(r0 + lr) * KDIM + kb + gs * 8, &Asm[bf][r0 * BK]);
    }
    #pragma unroll
    for (int c = 0; c < BCALLS; c++) {
      const int r0 = (wid * BCALLS + c) * RPC;
      if (r0 < BN)
        gload16(Bbase + (size_t)(r0 + lr) * KDIM + kb + gs * 8, &Bsm[bf][r0 * BK]);
    }
  };

  auto compute = [&](int bf) {
    #pragma unroll
    for (int ks = 0; ks < KU; ks++) {
      short8 a[FM], b[FN];
      #pragma unroll
      for (int f = 0; f < FM; f++) {
        const int ra = wm * (BM / 4) + f * 16 + (lane & 15);
        const int ja = (ks * 4 + (lane >> 4)) ^ (ra & 7);
        a[f] = *(const short8*)(&Asm[bf][ra * BK + ja * 8]);
      }
      #pragma unroll
      for (int f = 0; f < FN; f++) {
        const int rb = wn * (BN / 2) + f * 16 + (lane & 15);
        const int jb = (ks * 4 + (lane >> 4)) ^ (rb & 7);
        b[f] = *(const short8*)(&Bsm[bf][rb * BK + jb * 8]);
      }
      #pragma unroll
      for (int fm = 0; fm < FM; fm++)
        #pragma unroll
        for (int fn = 0; fn < FN; fn++)
          acc[fm][fn] = __builtin_amdgcn_mfma_f32_16x16x32_bf16(a[fm], b[fn], acc[fm][fn], 0, 0, 0);
    }
  };

  stage(0, 0);
  __syncthreads();
  int cur = 0;
  for (int kb = BK; kb < KDIM; kb += BK) {
    stage(cur ^ 1, kb);
    compute(cur);
    __syncthreads();
    cur ^= 1;
  }
  compute(cur);

  #pragma unroll
  for (int fm = 0; fm < FM; fm++)
    #pragma unroll
    for (int fn = 0; fn < FN; fn++) {
      const int col = n0 + wn * (BN / 2) + fn * 16 + (lane & 15);
      const int rbase = m0 + wm * (BM / 4) + fm * 16 + (lane >> 4) * 4;
      #pragma unroll
      for (int r2 = 0; r2 < 4; r2++)
        C[(size_t)(rbase + r2) * NDIM + col] = acc[fm][fn][r2];
    }

  // fused per-column BN stats: per-wave column S/S2 -> LDS -> atomicAdd
  {
    __syncthreads();                   // all waves done with Asm/Bsm
    float* red = (float*)&Asm[0][0];   // [4 wm][2 st][BN col]
    #pragma unroll
    for (int fn = 0; fn < FN; fn++) {
      float s = 0.f, s2 = 0.f;
      #pragma unroll
      for (int fm = 0; fm < FM; fm++)
        #pragma unroll
        for (int r2 = 0; r2 < 4; r2++) {
          float v = acc[fm][fn][r2];
          s += v; s2 = fmaf(v, v, s2);
        }
      s += __shfl_xor(s, 16);  s += __shfl_xor(s, 32);
      s2 += __shfl_xor(s2, 16); s2 += __shfl_xor(s2, 32);
      if ((lane >> 4) == 0) {
        const int colL = wn * (BN / 2) + fn * 16 + (lane & 15);   // 0..BN-1
        red[wm * (2 * BN) + colL] = s;
        red[wm * (2 * BN) + BN + colL] = s2;
      }
    }
    __syncthreads();
    if (tid < 2 * BN) {
      const int colL = tid % BN, st = tid / BN;
      float v = red[st * BN + colL] + red[2 * BN + st * BN + colL]
              + red[4 * BN + st * BN + colL] + red[6 * BN + st * BN + colL];
      atomicAdd(&stats[(size_t)st * NDIM + n0 + colL], v);
    }
  }
}

// ---- final: bn3 (inline from S/S2) + transpose + identity + relu ----
__global__ __launch_bounds__(256) void tfinal_kernel(const float* __restrict__ out3,
    const float* __restrict__ g, const float* __restrict__ bb,
    const float* __restrict__ Sacc, const float* __restrict__ x,
    float* __restrict__ out)
{
  __shared__ float t[64 * 199];
  __shared__ float ssl[128];
  const int b = blockIdx.x >> 4, n0 = (blockIdx.x & 15) * 64;
  if (threadIdx.x < 64) {
    const int ch = n0 + threadIdx.x;
    float S = Sacc[ch], S2 = Sacc[1024 + ch];
    float mean = S * (1.f / 6272.f);
    float var = S2 * (1.f / 6272.f) - mean * mean;
    float sc = g[ch] * rsqrtf(var + EPSV);
    ssl[threadIdx.x] = sc; ssl[64 + threadIdx.x] = bb[ch] - mean * sc;
  }
  __syncthreads();
  for (int idx = threadIdx.x; idx < 196 * 64; idx += 256) {
    int p = idx >> 6, ni = idx & 63;
    float v = out3[(size_t)(b * 196 + p) * 1024 + n0 + ni] * ssl[ni] + ssl[64 + ni];
    t[ni * 199 + p] = v;
  }
  __syncthreads();
  for (int idx = threadIdx.x; idx < 64 * 196; idx += 256) {
    int ni = idx / 196, p = idx - ni * 196;
    size_t o = (size_t)(b * 1024 + n0 + ni) * 196 + p;
    out[o] = fmaxf(t[ni * 199 + p] + x[o], 0.f);
  }
}

// ============================================================================
// FALLBACK PATH (round-2 proven kernels, used only if ws_size is too small)
// ============================================================================

template<int CIN, int OUT, bool APPLY_BN>
__global__ __launch_bounds__(256) void amm1x1_kernel(
    const float* __restrict__ xin, const float* __restrict__ ss,
    const float* __restrict__ cent, const float* __restrict__ lut,
    const float* __restrict__ invt, float* __restrict__ outbuf)
{
  constexpr int NCB = CIN / 4;
  constexpr int NO = OUT / 256;
  __shared__ float vsm[CIN * 14];
  __shared__ __align__(16) float attn_sm[14 * 16];
  const int tid = threadIdx.x;
  const int b = blockIdx.x / 14, y = blockIdx.x % 14;
  const int rowbase = y * 14;
  for (int e = tid; e < CIN * 14; e += 256) {
    int c = e / 14, xc = e - c * 14;
    float v = xin[(b * CIN + c) * 196 + rowbase + xc];
    if (APPLY_BN) v = fmaxf(v * ss[c] + ss[CIN + c], 0.f);
    vsm[e] = v;
  }
  __syncthreads();
  float acc[14 * NO];
  #pragma unroll
  for (int i = 0; i < 14 * NO; i++) acc[i] = 0.f;
  const float it = invt[0];
  const int p_ = tid >> 4, k_ = tid & 15;
  for (int cb = 0; cb < NCB; ++cb) {
    if (tid < 224) {
      const float* cc = cent + (cb * 16 + k_) * 4;
      float s = 0.f;
      #pragma unroll
      for (int si = 0; si < 4; si++) {
        float cv = cc[si];
        float vv = vsm[(cb * 4 + si) * 14 + p_];
        s = fmaf(cv, 2.f * vv - cv, s);
      }
      s *= it;
      float m = s;
      #pragma unroll
      for (int off = 8; off; off >>= 1) m = fmaxf(m, __shfl_xor(m, off, 16));
      float e = __expf(s - m);
      float sum = e;
      #pragma unroll
      for (int off = 8; off; off >>= 1) sum += __shfl_xor(sum, off, 16);
      attn_sm[p_ * 16 + k_] = e / sum;
    }
    __syncthreads();
    float lv[NO][16];
    #pragma unroll
    for (int j = 0; j < NO; j++)
      #pragma unroll
      for (int k = 0; k < 16; k++)
        lv[j][k] = lut[(cb * 16 + k) * OUT + j * 256 + tid];
    const float4* a4 = (const float4*)attn_sm;
    #pragma unroll
    for (int p = 0; p < 14; p++) {
      float4 q0 = a4[p*4+0], q1 = a4[p*4+1], q2 = a4[p*4+2], q3 = a4[p*4+3];
      float av[16] = {q0.x,q0.y,q0.z,q0.w, q1.x,q1.y,q1.z,q1.w,
                      q2.x,q2.y,q2.z,q2.w, q3.x,q3.y,q3.z,q3.w};
      #pragma unroll
      for (int j = 0; j < NO; j++) {
        float s = acc[p * NO + j];
        #pragma unroll
        for (int k = 0; k < 16; k++) s = fmaf(av[k], lv[j][k], s);
        acc[p * NO + j] = s;
      }
    }
    __syncthreads();
  }
  #pragma unroll
  for (int j = 0; j < NO; j++) {
    int o = j * 256 + tid;
    #pragma unroll
    for (int p = 0; p < 14; p++)
      outbuf[(b * OUT + o) * 196 + rowbase + p] = acc[p * NO + j];
  }
}

__global__ __launch_bounds__(256) void amm3x3_kernel(
    const float* __restrict__ xin, const float* __restrict__ ss,
    const float* __restrict__ cent, const float* __restrict__ lut,
    const float* __restrict__ invt, float* __restrict__ outbuf)
{
  __shared__ float vsm[256 * 3 * 16];
  __shared__ __align__(16) float attn_sm[14 * 16];
  const int tid = threadIdx.x;
  const int b = blockIdx.x / 14, y = blockIdx.x % 14;
  for (int e = tid; e < 256 * 3 * 16; e += 256) {
    int c = e / 48, rem = e - c * 48, i = rem >> 4, col = rem & 15;
    int yy = y + i - 1, xx = col - 1;
    float v = 0.f;
    if (yy >= 0 && yy < 14 && xx >= 0 && xx < 14) {
      v = xin[(b * 256 + c) * 196 + yy * 14 + xx];
      v = fmaxf(v * ss[c] + ss[256 + c], 0.f);
    }
    vsm[e] = v;
  }
  __syncthreads();
  float acc[14];
  #pragma unroll
  for (int i = 0; i < 14; i++) acc[i] = 0.f;
  const float it = invt[0];
  const int p_ = tid >> 4, k_ = tid & 15;
  for (int cb = 0; cb < 256; ++cb) {
    if (tid < 224) {
      const float* cc = cent + (cb * 16 + k_) * 9;
      float s = 0.f;
      #pragma unroll
      for (int i = 0; i < 3; i++)
        #pragma unroll
        for (int j = 0; j < 3; j++) {
          float cv = cc[i * 3 + j];
          float vv = vsm[(cb * 3 + i) * 16 + p_ + j];
          s = fmaf(cv, 2.f * vv - cv, s);
        }
      s *= it;
      float m = s;
      #pragma unroll
      for (int off = 8; off; off >>= 1) m = fmaxf(m, __shfl_xor(m, off, 16));
      float e = __expf(s - m);
      float sum = e;
      #pragma unroll
      for (int off = 8; off; off >>= 1) sum += __shfl_xor(sum, off, 16);
      attn_sm[p_ * 16 + k_] = e / sum;
    }
    __syncthreads();
    float lv[16];
    #pragma unroll
    for (int k = 0; k < 16; k++) lv[k] = lut[(cb * 16 + k) * 256 + tid];
    const float4* a4 = (const float4*)attn_sm;
    #pragma unroll
    for (int p = 0; p < 14; p++) {
      float4 q0 = a4[p*4+0], q1 = a4[p*4+1], q2 = a4[p*4+2], q3 = a4[p*4+3];
      float av[16] = {q0.x,q0.y,q0.z,q0.w, q1.x,q1.y,q1.z,q1.w,
                      q2.x,q2.y,q2.z,q2.w, q3.x,q3.y,q3.z,q3.w};
      float s = acc[p];
      #pragma unroll
      for (int k = 0; k < 16; k++) s = fmaf(av[k], lv[k], s);
      acc[p] = s;
    }
    __syncthreads();
  }
  #pragma unroll
  for (int p = 0; p < 14; p++)
    outbuf[(b * 256 + tid) * 196 + y * 14 + p] = acc[p];
}

template<int CH>
__global__ __launch_bounds__(256) void bnstats_kernel(const float* __restrict__ buf,
    const float* __restrict__ g, const float* __restrict__ bb, float* __restrict__ ss)
{
  const int c = blockIdx.x, tid = threadIdx.x;
  float s = 0.f, s2 = 0.f;
  for (int e = tid; e < 32 * 196; e += 256) {
    int bi = e / 196, l = e - bi * 196;
    float v = buf[(bi * CH + c) * 196 + l];
    s += v; s2 = fmaf(v, v, s2);
  }
  #pragma unroll
  for (int off = 32; off; off >>= 1) { s += __shfl_down(s, off); s2 += __shfl_down(s2, off); }
  __shared__ float red[8];
  int w = tid >> 6;
  if ((tid & 63) == 0) { red[w] = s; red[4 + w] = s2; }
  __syncthreads();
  if (tid == 0) {
    float S  = red[0] + red[1] + red[2] + red[3];
    float S2 = red[4] + red[5] + red[6] + red[7];
    float mean = S * (1.f / 6272.f);
    float var  = S2 * (1.f / 6272.f) - mean * mean;
    float sc = g[c] * rsqrtf(var + EPSV);
    ss[c] = sc;
    ss[CH + c] = bb[c] - mean * sc;
  }
}

__global__ __launch_bounds__(256) void final_old_kernel(float* __restrict__ out3,
    const float* __restrict__ ss, const float* __restrict__ x)
{
  const int total = 32 * 1024 * 196;
  for (int idx = blockIdx.x * 256 + threadIdx.x; idx < total; idx += gridDim.x * 256) {
    int c = (idx / 196) & 1023;
    float v = out3[idx] * ss[c] + ss[1024 + c] + x[idx];
    out3[idx] = fmaxf(v, 0.f);
  }
}

// ============================================================================

extern "C" void kernel_launch(void* const* d_in, const int* in_sizes, int n_in,
                              void* d_out, int out_size, void* d_ws, size_t ws_size,
                              hipStream_t stream) {
  const float* x   = (const float*)d_in[0];
  const float* c1c = (const float*)d_in[1];
  const float* c1l = (const float*)d_in[2];
  const float* c1t = (const float*)d_in[3];
  const float* c2c = (const float*)d_in[4];
  const float* c2l = (const float*)d_in[5];
  const float* c2t = (const float*)d_in[6];
  const float* c3c = (const float*)d_in[7];
  const float* c3l = (const float*)d_in[8];
  const float* c3t = (const float*)d_in[9];
  const float* g1  = (const float*)d_in[10];
  const float* b1  = (const float*)d_in[11];
  const float* g2  = (const float*)d_in[12];
  const float* b2  = (const float*)d_in[13];
  const float* g3  = (const float*)d_in[14];
  const float* b3  = (const float*)d_in[15];

  float* ws = (float*)d_ws;
  const size_t FAST_NEED = 24255488ull * 4ull;   // ~97 MB (known-good layout)

  if (ws_size >= FAST_NEED) {
    // ---- fast MFMA path ----
    u16*   attnB = (u16*)ws;                         // 25,690,112 u16 (51 MB)
    float* out3  = ws + 12845056;                    // 6,422,528 f region (out3 uses 1st slot)
    float* out1  = out3 + 6422528;                   // 1,605,632 f
    float* out2  = out1 + 1605632;                   // 1,605,632 f
    bf16*  lutT1 = (bf16*)(out2 + 1605632);          // 1,048,576 u16
    bf16*  lutT2 = lutT1 + 1048576;
    bf16*  lutT3 = lutT2 + 1048576;
    float* acc1  = (float*)(lutT3 + 1048576);        // 512 f (S,S2 for bn1)
    float* acc2  = acc1 + 512;                       // 512 f
    float* acc3  = acc2 + 512;                       // 2048 f

    // fused attn1 + lut transposes + acc zeroing (block 1792)
    prep_kernel<<<1793, 256, 0, stream>>>(x, c1c, c1t, attnB,
                                          c1l, lutT1, c2l, lutT2, c3l, lutT3, acc1);

    // layer 1: no split-K (BN=64, grid 196); stats fused into epilogue
    gemm_kernel<4096, 256, 128, 64, 64><<<196, 512, 0, stream>>>(
        attnB, (const u16*)lutT1, out1, acc1);

    // layer 2 (attn2 computes bn1 inline from acc1)
    attn2_kernel<<<512, 256, 0, stream>>>(out1, g1, b1, acc1, c2c, c2t, attnB);
    gemm_kernel<4096, 256, 128, 64, 64><<<196, 512, 0, stream>>>(
        attnB, (const u16*)lutT2, out2, acc2);

    // layer 3 (attn3 computes bn2 inline from acc2); gemm3 fuses bn3 stats
    attn3_kernel<<<392, 256, 0, stream>>>(out2, g2, b2, acc2, c3c, c3t, (bf16*)attnB);
    gemm_kernel<1024, 1024, 128, 128, 64><<<392, 512, 0, stream>>>(
        attnB, (const u16*)lutT3, out3, acc3);

    // final (bn3 inline from acc3)
    tfinal_kernel<<<512, 256, 0, stream>>>(out3, g3, b3, acc3, x, (float*)d_out);
  } else {
    // ---- fallback (round-2 proven path) ----
    float* out3 = (float*)d_out;
    float* out1 = ws;
    float* out2 = out1 + 32 * 256 * 196;
    float* ss1  = out2 + 32 * 256 * 196;
    float* ss2  = ss1 + 512;
    float* ss3  = ss2 + 512;

    amm1x1_kernel<1024, 256, false><<<448, 256, 0, stream>>>(x, nullptr, c1c, c1l, c1t, out1);
    bnstats_kernel<256><<<256, 256, 0, stream>>>(out1, g1, b1, ss1);
    amm3x3_kernel<<<448, 256, 0, stream>>>(out1, ss1, c2c, c2l, c2t, out2);
    bnstats_kernel<256><<<256, 256, 0, stream>>>(out2, g2, b2, ss2);
    amm1x1_kernel<256, 1024, true><<<448, 256, 0, stream>>>(out2, ss2, c3c, c3l, c3t, out3);
    bnstats_kernel<1024><<<1024, 256, 0, stream>>>(out3, g3, b3, ss3);
    final_old_kernel<<<2048, 256, 0, stream>>>(out3, ss3, x);
  }
}

// Round 12
// 261.477 us; speedup vs baseline: 1.1113x; 1.1113x over previous
//
#include <hip/hip_runtime.h>
#include <hip/hip_bf16.h>

#define EPSV 1e-5f

typedef unsigned short u16;
typedef __attribute__((ext_vector_type(8))) short short8;
typedef __attribute__((ext_vector_type(4))) float f32x4;
typedef __hip_bfloat16 bf16;

__device__ __forceinline__ unsigned int pack2(float a, float b) {
  bf16 ha = __float2bfloat16(a), hb = __float2bfloat16(b);
  u16 ua, ub;
  __builtin_memcpy(&ua, &ha, 2);
  __builtin_memcpy(&ub, &hb, 2);
  return (unsigned int)ua | ((unsigned int)ub << 16);
}

// async global->LDS, 16B per lane; LDS dest = wave-uniform base + lane*16
typedef __attribute__((address_space(1))) const void gvoid_t;
typedef __attribute__((address_space(3))) void lvoid_t;
__device__ __forceinline__ void gload16(const void* g, void* l) {
  __builtin_amdgcn_global_load_lds((gvoid_t*)g, (lvoid_t*)l, 16, 0, 0);
}

// ============================================================================
// FAST PATH (MFMA) — position-major intermediates [M=6272, C]
// ============================================================================

// ---- prep: fused attn layer-1 (blocks 0..1023) + lut transpose (blocks 1024..1791)
__global__ __launch_bounds__(256) void prep_kernel(
    const float* __restrict__ x, const float* __restrict__ cent,
    const float* __restrict__ invt, u16* __restrict__ attn,
    const float* __restrict__ s1, bf16* __restrict__ d1,
    const float* __restrict__ s2, bf16* __restrict__ d2,
    const float* __restrict__ s3, bf16* __restrict__ d3)
{
  __shared__ __align__(16) float sh[7012];   // attn1: 6468+544; lutT: 64*65=4160
  const int tid = threadIdx.x;
  if (blockIdx.x >= 1024) {
    // ---------------- lutT part ----------------
    const int bid = blockIdx.x - 1024;
    const int which = bid >> 8, sub = bid & 255;
    const float* in = (which == 0) ? s1 : (which == 1) ? s2 : s3;
    bf16* out = (which == 0) ? d1 : (which == 1) ? d2 : d3;
    const int K = (which == 2) ? 1024 : 4096;
    const int N = (which == 2) ? 1024 : 256;
    const int kt = K >> 6;
    const int bk = sub & (kt - 1), bn = sub / kt;
    const int k0 = bk * 64, n0 = bn * 64;
    float* t = sh;                           // [64][65]
    for (int idx = tid; idx < 4096; idx += 256) {
      int r = idx >> 6, c = idx & 63;
      t[r * 65 + c] = in[(size_t)(k0 + r) * N + n0 + c];
    }
    __syncthreads();
    for (int idx = tid; idx < 4096; idx += 256) {
      int r = idx >> 6, c = idx & 63;
      out[(size_t)(n0 + r) * K + k0 + c] = __float2bfloat16(t[c * 65 + r]);
    }
    return;
  }
  // ---------------- attn1 part ----------------
  float* vs = sh;                            // [196][33] position-major
  float* cs = sh + 6468;                     // [8][68]
  const int bi = blockIdx.x >> 5, cg = blockIdx.x & 31;   // image, 8-cb group
  const float* xb = x + ((size_t)bi * 1024 + cg * 32) * 196;
  for (int e = tid; e < 3136; e += 256) {    // 32 ch x 98 float2
    int c = e / 98, p2 = e - c * 98;
    float2 w = *(const float2*)&xb[(size_t)c * 196 + p2 * 2];
    vs[(p2 * 2) * 33 + c] = w.x;
    vs[(p2 * 2 + 1) * 33 + c] = w.y;
  }
  if (tid < 128) {
    int cb = tid >> 4, kk = tid & 15;
    *(float4*)&cs[cb * 68 + kk * 4] =
        *(const float4*)&cent[(size_t)(cg * 8 + cb) * 64 + kk * 4];
  }
  __syncthreads();
  const float it = invt[0];
  const int cbL = tid & 7, pj = tid >> 3;    // codebook lane, 32 position slots
  float4 cv[16]; float cn[16];
  #pragma unroll
  for (int k = 0; k < 16; k++) {
    cv[k] = *(const float4*)&cs[cbL * 68 + k * 4];
    cn[k] = cv[k].x * cv[k].x + cv[k].y * cv[k].y + cv[k].z * cv[k].z + cv[k].w * cv[k].w;
  }
  for (int p = pj; p < 196; p += 32) {
    const float* vp = &vs[p * 33 + cbL * 4];
    const float v0 = vp[0], v1 = vp[1], v2 = vp[2], v3 = vp[3];
    float s[16], mx = -3e38f;
    #pragma unroll
    for (int k = 0; k < 16; k++) {
      float d = v0 * cv[k].x + v1 * cv[k].y + v2 * cv[k].z + v3 * cv[k].w;
      s[k] = it * (2.f * d - cn[k]);
      mx = fmaxf(mx, s[k]);
    }
    float sum = 0.f;
    #pragma unroll
    for (int k = 0; k < 16; k++) { float e = __expf(s[k] - mx); s[k] = e; sum += e; }
    const float r = 1.f / sum;
    uint4 w0, w1;
    w0.x = pack2(s[0] * r,  s[1] * r);  w0.y = pack2(s[2] * r,  s[3] * r);
    w0.z = pack2(s[4] * r,  s[5] * r);  w0.w = pack2(s[6] * r,  s[7] * r);
    w1.x = pack2(s[8] * r,  s[9] * r);  w1.y = pack2(s[10] * r, s[11] * r);
    w1.z = pack2(s[12] * r, s[13] * r); w1.w = pack2(s[14] * r, s[15] * r);
    uint4* dst = (uint4*)(attn + (size_t)(bi * 196 + p) * 4096 + (cg * 8 + cbL) * 16);
    dst[0] = w0; dst[1] = w1;
  }
}

// ---- attn layer 2 (3x3) v4: block = full image x 16-cb group; grid 512 ----
__global__ __launch_bounds__(256) void attn2_kernel(const float* __restrict__ out1,
    const float* __restrict__ g, const float* __restrict__ bb,
    const float* __restrict__ Sacc, const float* __restrict__ cent,
    const float* __restrict__ invt, u16* __restrict__ attn)
{
  __shared__ float vs[16 * 16 * 16];            // 16 KB [ry][rx][ch], ring = 0
  __shared__ __align__(16) float cs[16 * 196];  // 12.25 KB [cb][k*12+j] (2*it*c)
  __shared__ float cnl[16 * 17];                // it*||c||^2
  __shared__ float ssl[32];                     // [0..15]=scale, [16..31]=shift
  const int tid = threadIdx.x;
  const int bi = blockIdx.x >> 4, cg = blockIdx.x & 15;
  const float it = invt[0];
  if (tid < 16) {
    const int ch = cg * 16 + tid;
    float S = Sacc[ch], S2 = Sacc[256 + ch];
    float mean = S * (1.f / 6272.f);
    float var = S2 * (1.f / 6272.f) - mean * mean;
    float sc = g[ch] * rsqrtf(var + EPSV);
    ssl[tid] = sc; ssl[16 + tid] = bb[ch] - mean * sc;
  }
  for (int e = tid; e < 4096; e += 256) vs[e] = 0.f;
  const float it2 = 2.f * it;
  for (int idx = tid; idx < 576; idx += 256) {
    int cb = idx / 36, f4i = idx - cb * 36;
    float4 w = *(const float4*)&cent[(size_t)(cg * 16 + cb) * 144 + f4i * 4];
    int j0 = f4i * 4;
    #pragma unroll
    for (int t = 0; t < 4; t++) {
      int j = j0 + t, k = j / 9, jj = j - k * 9;
      cs[cb * 196 + k * 12 + jj] = it2 * ((const float*)&w)[t];
    }
  }
  {
    int cb = tid >> 4, k = tid & 15;
    const float* cc = &cent[(size_t)(cg * 16 + cb) * 144 + k * 9];
    float cn = 0.f;
    #pragma unroll
    for (int j = 0; j < 9; j++) cn = fmaf(cc[j], cc[j], cn);
    cnl[cb * 17 + k] = it * cn;
  }
  __syncthreads();                              // ring zero + ssl complete
  for (int e = tid; e < 784; e += 256) {
    int p = e >> 2, c4 = e & 3;
    int r = p / 14, xc = p - r * 14;
    float4 w = *(const float4*)&out1[(size_t)(bi * 196 + p) * 256 + cg * 16 + c4 * 4];
    float* dst = &vs[((r + 1) * 16 + (xc + 1)) * 16 + c4 * 4];
    dst[0] = fmaxf(w.x * ssl[c4 * 4 + 0] + ssl[16 + c4 * 4 + 0], 0.f);
    dst[1] = fmaxf(w.y * ssl[c4 * 4 + 1] + ssl[16 + c4 * 4 + 1], 0.f);
    dst[2] = fmaxf(w.z * ssl[c4 * 4 + 2] + ssl[16 + c4 * 4 + 2], 0.f);
    dst[3] = fmaxf(w.w * ssl[c4 * 4 + 3] + ssl[16 + c4 * 4 + 3], 0.f);
  }
  __syncthreads();
  const int cb = tid & 15, pj = tid >> 4;       // codebook lane, 16 pos slots
  for (int i0 = 0; i0 < 13; i0 += 2) {
    const int p0 = pj + (i0 << 4);
    const int p1 = pj + ((i0 + 1) << 4);
    const int np = (p1 < 196) ? 2 : ((p0 < 196) ? 1 : 0);
    if (np == 0) break;
    float v[2][9];
    #pragma unroll
    for (int i = 0; i < 2; i++) if (i < np) {
      const int p = i ? p1 : p0;
      const int r = p / 14, xc = p - r * 14;
      #pragma unroll
      for (int dy = 0; dy < 3; dy++)
        #pragma unroll
        for (int dx = 0; dx < 3; dx++)
          v[i][dy * 3 + dx] = vs[((r + dy) * 16 + xc + dx) * 16 + cb];
    }
    float s[2][16];
    #pragma unroll
    for (int k = 0; k < 16; k++) {
      const float* ck = &cs[cb * 196 + k * 12];
      const float4 ca = *(const float4*)ck;
      const float4 cbv = *(const float4*)(ck + 4);
      const float c8 = ck[8];
      const float cnv = cnl[cb * 17 + k];
      float c9[9] = {ca.x, ca.y, ca.z, ca.w, cbv.x, cbv.y, cbv.z, cbv.w, c8};
      #pragma unroll
      for (int i = 0; i < 2; i++) if (i < np) {
        float d = -cnv;
        #pragma unroll
        for (int j = 0; j < 9; j++) d = fmaf(c9[j], v[i][j], d);
        s[i][k] = d;
      }
    }
    #pragma unroll
    for (int i = 0; i < 2; i++) if (i < np) {
      const int p = i ? p1 : p0;
      float mx = -3e38f;
      #pragma unroll
      for (int k = 0; k < 16; k++) mx = fmaxf(mx, s[i][k]);
      float sum = 0.f;
      #pragma unroll
      for (int k = 0; k < 16; k++) { float e = __expf(s[i][k] - mx); s[i][k] = e; sum += e; }
      const float r = 1.f / sum;
      uint4 w0, w1;
      w0.x = pack2(s[i][0] * r,  s[i][1] * r);  w0.y = pack2(s[i][2] * r,  s[i][3] * r);
      w0.z = pack2(s[i][4] * r,  s[i][5] * r);  w0.w = pack2(s[i][6] * r,  s[i][7] * r);
      w1.x = pack2(s[i][8] * r,  s[i][9] * r);  w1.y = pack2(s[i][10] * r, s[i][11] * r);
      w1.z = pack2(s[i][12] * r, s[i][13] * r); w1.w = pack2(s[i][14] * r, s[i][15] * r);
      uint4* dst = (uint4*)(attn + (size_t)(bi * 196 + p) * 4096 + (cg * 16 + cb) * 16);
      dst[0] = w0; dst[1] = w1;
    }
  }
}

// ---- attn layer 3: BN2 computed inline from atomic S/S2 ----
__global__ __launch_bounds__(256) void attn3_kernel(const float* __restrict__ out2,
    const float* __restrict__ g, const float* __restrict__ bb,
    const float* __restrict__ Sacc, const float* __restrict__ cent,
    const float* __restrict__ invt, bf16* __restrict__ attn)
{
  __shared__ float ssl[512];                 // [0..255]=scale, [256..511]=shift
  const int t = threadIdx.x;
  {
    float S = Sacc[t], S2 = Sacc[256 + t];
    float mean = S * (1.f / 6272.f);
    float var = S2 * (1.f / 6272.f) - mean * mean;
    float sc = g[t] * rsqrtf(var + EPSV);
    ssl[t] = sc; ssl[256 + t] = bb[t] - mean * sc;
  }
  __syncthreads();
  const int cb = t & 63, ml = t >> 6;
  const int m0 = blockIdx.x * 16;
  const float it = invt[0];
  float4 cv[16]; float cn[16];
  const float4* cc = (const float4*)(cent + cb * 64);
  #pragma unroll
  for (int k = 0; k < 16; k++) {
    cv[k] = cc[k];
    cn[k] = cv[k].x * cv[k].x + cv[k].y * cv[k].y + cv[k].z * cv[k].z + cv[k].w * cv[k].w;
  }
  const float4 scv = *(const float4*)(ssl + cb * 4);
  const float4 shv = *(const float4*)(ssl + 256 + cb * 4);
  for (int gi = 0; gi < 4; gi++) {
    const int m = m0 + gi * 4 + ml;
    float4 xv = *(const float4*)(out2 + (size_t)m * 256 + cb * 4);
    float4 v;
    v.x = fmaxf(xv.x * scv.x + shv.x, 0.f);
    v.y = fmaxf(xv.y * scv.y + shv.y, 0.f);
    v.z = fmaxf(xv.z * scv.z + shv.z, 0.f);
    v.w = fmaxf(xv.w * scv.w + shv.w, 0.f);
    float s[16], mx = -3e38f;
    #pragma unroll
    for (int k = 0; k < 16; k++) {
      float d = v.x * cv[k].x + v.y * cv[k].y + v.z * cv[k].z + v.w * cv[k].w;
      s[k] = it * (2.f * d - cn[k]);
      mx = fmaxf(mx, s[k]);
    }
    float sum = 0.f;
    #pragma unroll
    for (int k = 0; k < 16; k++) { float e = __expf(s[k] - mx); s[k] = e; sum += e; }
    float r = 1.f / sum;
    #pragma unroll
    for (int k = 0; k < 16; k++)
      attn[(size_t)m * 1024 + cb * 16 + k] = __float2bfloat16(s[k] * r);
  }
}

// ---- bf16 MFMA GEMM: 128x128 tile, BK=64, 8 waves (4m x 2n, 512 thr),
//      DOUBLE-BUFFERED global_load_lds(16B), XCD-aware swizzle, optional fused
//      BN-stats epilogue. (R10-proven configuration; grid >= 392 required.)
template<int KDIM, int NT, int KSLICES, int BM, int BK>
__global__ __launch_bounds__(512) void gemm_kernel(const u16* __restrict__ A,
    const u16* __restrict__ Bt, float* __restrict__ C, size_t cstride,
    float* __restrict__ zacc, int zn, float* __restrict__ stats)
{
  constexpr int NDIM = NT * 128;
  constexpr int KS = KDIM / KSLICES;
  constexpr int MT = 6272 / BM;
  constexpr int FM = BM / 64;          // A fragments per wave (wave tile BM/4 x 64)
  constexpr int KU = BK / 32;
  constexpr int SLOTS = BK / 8;        // 16B slots per LDS row
  constexpr int RPC = 64 / SLOTS;      // rows covered per gload16 call (8)
  constexpr int ACALLS = BM / (RPC * 8);
  constexpr int BCALLS = 128 / (RPC * 8);
  __shared__ __align__(16) u16 Asm[2][BM * BK];
  __shared__ __align__(16) u16 Bsm[2][128 * BK];
  const int tid = threadIdx.x;
  if (blockIdx.x == 0 && zacc) {
    for (int i = tid; i < zn; i += 512) zacc[i] = 0.f;
  }
  const int nwg = gridDim.x;
  int wg = blockIdx.x;
  if ((nwg & 7) == 0) wg = (blockIdx.x & 7) * (nwg >> 3) + (blockIdx.x >> 3);
  const int nt = wg % NT;
  const int mt = (wg / NT) % MT;
  const int sl = wg / (NT * MT);
  const int kbeg = sl * KS, kend = kbeg + KS;
  const int m0 = mt * BM, n0 = nt * 128;
  const int lane = tid & 63, wid = tid >> 6;   // 8 waves
  const int wm = wid >> 1, wn = wid & 1;       // 4m x 2n; wave tile 32x64
  const int lr = lane / SLOTS, sslot = lane % SLOTS;
  const int gs = sslot ^ (lr & 7);     // inverse-swizzled source slot

  f32x4 acc[FM][4];
  #pragma unroll
  for (int i = 0; i < FM; i++)
    #pragma unroll
    for (int j = 0; j < 4; j++) acc[i][j] = (f32x4){0.f, 0.f, 0.f, 0.f};

  const u16* Abase = A + (size_t)m0 * KDIM;
  const u16* Bbase = Bt + (size_t)n0 * KDIM;

  auto stage = [&](int bf, int kb) {
    #pragma unroll
    for (int c = 0; c < ACALLS; c++) {
      const int r0 = (wid * ACALLS + c) * RPC;
      gload16(Abase + (size_t)(r0 + lr) * KDIM + kb + gs * 8, &Asm[bf][r0 * BK]);
    }
    #pragma unroll
    for (int c = 0; c < BCALLS; c++) {
      const int r0 = (wid * BCALLS + c) * RPC;
      gload16(Bbase + (size_t)(r0 + lr) * KDIM + kb + gs * 8, &Bsm[bf][r0 * BK]);
    }
  };

  auto compute = [&](int bf) {
    #pragma unroll
    for (int ks = 0; ks < KU; ks++) {
      short8 a[FM], b[4];
      #pragma unroll
      for (int f = 0; f < FM; f++) {
        const int ra = wm * (BM / 4) + f * 16 + (lane & 15);
        const int ja = (ks * 4 + (lane >> 4)) ^ (ra & 7);
        a[f] = *(const short8*)(&Asm[bf][ra * BK + ja * 8]);
      }
      #pragma unroll
      for (int f = 0; f < 4; f++) {
        const int rb = wn * 64 + f * 16 + (lane & 15);
        const int jb = (ks * 4 + (lane >> 4)) ^ (rb & 7);
        b[f] = *(const short8*)(&Bsm[bf][rb * BK + jb * 8]);
      }
      #pragma unroll
      for (int fm = 0; fm < FM; fm++)
        #pragma unroll
        for (int fn = 0; fn < 4; fn++)
          acc[fm][fn] = __builtin_amdgcn_mfma_f32_16x16x32_bf16(a[fm], b[fn], acc[fm][fn], 0, 0, 0);
    }
  };

  stage(0, kbeg);
  __syncthreads();
  int cur = 0;
  for (int kb = kbeg + BK; kb < kend; kb += BK) {
    stage(cur ^ 1, kb);
    compute(cur);
    __syncthreads();
    cur ^= 1;
  }
  compute(cur);

  float* __restrict__ Cs = C + (size_t)sl * cstride;
  #pragma unroll
  for (int fm = 0; fm < FM; fm++)
    #pragma unroll
    for (int fn = 0; fn < 4; fn++) {
      const int col = n0 + wn * 64 + fn * 16 + (lane & 15);
      const int rbase = m0 + wm * (BM / 4) + fm * 16 + (lane >> 4) * 4;
      #pragma unroll
      for (int r = 0; r < 4; r++)
        Cs[(size_t)(rbase + r) * NDIM + col] = acc[fm][fn][r];
    }

  // fused per-column BN stats (gemm3): per-wave column S/S2 -> LDS -> atomicAdd
  if (stats) {
    __syncthreads();                   // all waves done with Asm/Bsm
    float* red = (float*)&Asm[0][0];   // [4 wm][2 st][128 col] = 1024 f
    #pragma unroll
    for (int fn = 0; fn < 4; fn++) {
      float s = 0.f, s2 = 0.f;
      #pragma unroll
      for (int fm = 0; fm < FM; fm++)
        #pragma unroll
        for (int r = 0; r < 4; r++) {
          float v = acc[fm][fn][r];
          s += v; s2 = fmaf(v, v, s2);
        }
      s += __shfl_xor(s, 16);  s += __shfl_xor(s, 32);
      s2 += __shfl_xor(s2, 16); s2 += __shfl_xor(s2, 32);
      if ((lane >> 4) == 0) {
        const int colL = wn * 64 + fn * 16 + (lane & 15);   // 0..127
        red[wm * 256 + colL] = s;
        red[wm * 256 + 128 + colL] = s2;
      }
    }
    __syncthreads();
    if (tid < 256) {
      const int colL = tid & 127, st = (tid >> 7) & 1;
      float v = red[st * 128 + colL] + red[256 + st * 128 + colL]
              + red[512 + st * 128 + colL] + red[768 + st * 128 + colL];
      atomicAdd(&stats[(size_t)st * NDIM + n0 + colL], v);
    }
  }
}

// ---- BN stats stage 1 (vectorized): sums NSUM=4 split-K partials with float4
//      loads, writes summed buffer, LDS-reduces 4 row-groups, atomic S/S2 out.
//      grid 196, 256 threads; forward values (sum_out) bit-identical to scalar.
__global__ __launch_bounds__(256) void bnpart_kernel(const float* __restrict__ buf,
    float* __restrict__ sum_out, float* __restrict__ acc)
{
  constexpr int ROWS = 32;                 // 6272 / 196
  constexpr size_t PSTR = 6272ull * 256;
  __shared__ float red[4][512];            // [rg][ch]=S, [rg][256+ch]=S2
  const int t = threadIdx.x;
  const int c4 = (t & 63) * 4, rg = t >> 6;
  const int m0 = blockIdx.x * ROWS;
  float4 s = {0.f, 0.f, 0.f, 0.f}, q = {0.f, 0.f, 0.f, 0.f};
  for (int i = rg; i < ROWS; i += 4) {
    const size_t ro = (size_t)(m0 + i) * 256 + c4;
    float4 v0 = *(const float4*)&buf[ro];
    float4 v1 = *(const float4*)&buf[PSTR + ro];
    float4 v2 = *(const float4*)&buf[2 * PSTR + ro];
    float4 v3 = *(const float4*)&buf[3 * PSTR + ro];
    float4 v;
    v.x = ((v0.x + v1.x) + v2.x) + v3.x;   // same add order as scalar version
    v.y = ((v0.y + v1.y) + v2.y) + v3.y;
    v.z = ((v0.z + v1.z) + v2.z) + v3.z;
    v.w = ((v0.w + v1.w) + v2.w) + v3.w;
    *(float4*)&sum_out[ro] = v;
    s.x += v.x; q.x = fmaf(v.x, v.x, q.x);
    s.y += v.y; q.y = fmaf(v.y, v.y, q.y);
    s.z += v.z; q.z = fmaf(v.z, v.z, q.z);
    s.w += v.w; q.w = fmaf(v.w, v.w, q.w);
  }
  red[rg][c4 + 0] = s.x; red[rg][c4 + 1] = s.y;
  red[rg][c4 + 2] = s.z; red[rg][c4 + 3] = s.w;
  red[rg][256 + c4 + 0] = q.x; red[rg][256 + c4 + 1] = q.y;
  red[rg][256 + c4 + 2] = q.z; red[rg][256 + c4 + 3] = q.w;
  __syncthreads();
  {
    float S  = red[0][t] + red[1][t] + red[2][t] + red[3][t];
    float S2 = red[0][256 + t] + red[1][256 + t] + red[2][256 + t] + red[3][256 + t];
    atomicAdd(&acc[t], S);
    atomicAdd(&acc[256 + t], S2);
  }
}

// ---- final: bn3 (inline from S/S2) + transpose + identity + relu ----
__global__ __launch_bounds__(256) void tfinal_kernel(const float* __restrict__ out3,
    const float* __restrict__ g, const float* __restrict__ bb,
    const float* __restrict__ Sacc, const float* __restrict__ x,
    float* __restrict__ out)
{
  __shared__ float t[64 * 199];
  __shared__ float ssl[128];
  const int b = blockIdx.x >> 4, n0 = (blockIdx.x & 15) * 64;
  if (threadIdx.x < 64) {
    const int ch = n0 + threadIdx.x;
    float S = Sacc[ch], S2 = Sacc[1024 + ch];
    float mean = S * (1.f / 6272.f);
    float var = S2 * (1.f / 6272.f) - mean * mean;
    float sc = g[ch] * rsqrtf(var + EPSV);
    ssl[threadIdx.x] = sc; ssl[64 + threadIdx.x] = bb[ch] - mean * sc;
  }
  __syncthreads();
  for (int idx = threadIdx.x; idx < 196 * 64; idx += 256) {
    int p = idx >> 6, ni = idx & 63;
    float v = out3[(size_t)(b * 196 + p) * 1024 + n0 + ni] * ssl[ni] + ssl[64 + ni];
    t[ni * 199 + p] = v;
  }
  __syncthreads();
  for (int idx = threadIdx.x; idx < 64 * 196; idx += 256) {
    int ni = idx / 196, p = idx - ni * 196;
    size_t o = (size_t)(b * 1024 + n0 + ni) * 196 + p;
    out[o] = fmaxf(t[ni * 199 + p] + x[o], 0.f);
  }
}

// ============================================================================
// FALLBACK PATH (round-2 proven kernels, used only if ws_size is too small)
// ============================================================================

template<int CIN, int OUT, bool APPLY_BN>
__global__ __launch_bounds__(256) void amm1x1_kernel(
    const float* __restrict__ xin, const float* __restrict__ ss,
    const float* __restrict__ cent, const float* __restrict__ lut,
    const float* __restrict__ invt, float* __restrict__ outbuf)
{
  constexpr int NCB = CIN / 4;
  constexpr int NO = OUT / 256;
  __shared__ float vsm[CIN * 14];
  __shared__ __align__(16) float attn_sm[14 * 16];
  const int tid = threadIdx.x;
  const int b = blockIdx.x / 14, y = blockIdx.x % 14;
  const int rowbase = y * 14;
  for (int e = tid; e < CIN * 14; e += 256) {
    int c = e / 14, xc = e - c * 14;
    float v = xin[(b * CIN + c) * 196 + rowbase + xc];
    if (APPLY_BN) v = fmaxf(v * ss[c] + ss[CIN + c], 0.f);
    vsm[e] = v;
  }
  __syncthreads();
  float acc[14 * NO];
  #pragma unroll
  for (int i = 0; i < 14 * NO; i++) acc[i] = 0.f;
  const float it = invt[0];
  const int p_ = tid >> 4, k_ = tid & 15;
  for (int cb = 0; cb < NCB; ++cb) {
    if (tid < 224) {
      const float* cc = cent + (cb * 16 + k_) * 4;
      float s = 0.f;
      #pragma unroll
      for (int si = 0; si < 4; si++) {
        float cv = cc[si];
        float vv = vsm[(cb * 4 + si) * 14 + p_];
        s = fmaf(cv, 2.f * vv - cv, s);
      }
      s *= it;
      float m = s;
      #pragma unroll
      for (int off = 8; off; off >>= 1) m = fmaxf(m, __shfl_xor(m, off, 16));
      float e = __expf(s - m);
      float sum = e;
      #pragma unroll
      for (int off = 8; off; off >>= 1) sum += __shfl_xor(sum, off, 16);
      attn_sm[p_ * 16 + k_] = e / sum;
    }
    __syncthreads();
    float lv[NO][16];
    #pragma unroll
    for (int j = 0; j < NO; j++)
      #pragma unroll
      for (int k = 0; k < 16; k++)
        lv[j][k] = lut[(cb * 16 + k) * OUT + j * 256 + tid];
    const float4* a4 = (const float4*)attn_sm;
    #pragma unroll
    for (int p = 0; p < 14; p++) {
      float4 q0 = a4[p*4+0], q1 = a4[p*4+1], q2 = a4[p*4+2], q3 = a4[p*4+3];
      float av[16] = {q0.x,q0.y,q0.z,q0.w, q1.x,q1.y,q1.z,q1.w,
                      q2.x,q2.y,q2.z,q2.w, q3.x,q3.y,q3.z,q3.w};
      #pragma unroll
      for (int j = 0; j < NO; j++) {
        float s = acc[p * NO + j];
        #pragma unroll
        for (int k = 0; k < 16; k++) s = fmaf(av[k], lv[j][k], s);
        acc[p * NO + j] = s;
      }
    }
    __syncthreads();
  }
  #pragma unroll
  for (int j = 0; j < NO; j++) {
    int o = j * 256 + tid;
    #pragma unroll
    for (int p = 0; p < 14; p++)
      outbuf[(b * OUT + o) * 196 + rowbase + p] = acc[p * NO + j];
  }
}

__global__ __launch_bounds__(256) void amm3x3_kernel(
    const float* __restrict__ xin, const float* __restrict__ ss,
    const float* __restrict__ cent, const float* __restrict__ lut,
    const float* __restrict__ invt, float* __restrict__ outbuf)
{
  __shared__ float vsm[256 * 3 * 16];
  __shared__ __align__(16) float attn_sm[14 * 16];
  const int tid = threadIdx.x;
  const int b = blockIdx.x / 14, y = blockIdx.x % 14;
  for (int e = tid; e < 256 * 3 * 16; e += 256) {
    int c = e / 48, rem = e - c * 48, i = rem >> 4, col = rem & 15;
    int yy = y + i - 1, xx = col - 1;
    float v = 0.f;
    if (yy >= 0 && yy < 14 && xx >= 0 && xx < 14) {
      v = xin[(b * 256 + c) * 196 + yy * 14 + xx];
      v = fmaxf(v * ss[c] + ss[256 + c], 0.f);
    }
    vsm[e] = v;
  }
  __syncthreads();
  float acc[14];
  #pragma unroll
  for (int i = 0; i < 14; i++) acc[i] = 0.f;
  const float it = invt[0];
  const int p_ = tid >> 4, k_ = tid & 15;
  for (int cb = 0; cb < 256; ++cb) {
    if (tid < 224) {
      const float* cc = cent + (cb * 16 + k_) * 9;
      float s = 0.f;
      #pragma unroll
      for (int i = 0; i < 3; i++)
        #pragma unroll
        for (int j = 0; j < 3; j++) {
          float cv = cc[i * 3 + j];
          float vv = vsm[(cb * 3 + i) * 16 + p_ + j];
          s = fmaf(cv, 2.f * vv - cv, s);
        }
      s *= it;
      float m = s;
      #pragma unroll
      for (int off = 8; off; off >>= 1) m = fmaxf(m, __shfl_xor(m, off, 16));
      float e = __expf(s - m);
      float sum = e;
      #pragma unroll
      for (int off = 8; off; off >>= 1) sum += __shfl_xor(sum, off, 16);
      attn_sm[p_ * 16 + k_] = e / sum;
    }
    __syncthreads();
    float lv[16];
    #pragma unroll
    for (int k = 0; k < 16; k++) lv[k] = lut[(cb * 16 + k) * 256 + tid];
    const float4* a4 = (const float4*)attn_sm;
    #pragma unroll
    for (int p = 0; p < 14; p++) {
      float4 q0 = a4[p*4+0], q1 = a4[p*4+1], q2 = a4[p*4+2], q3 = a4[p*4+3];
      float av[16] = {q0.x,q0.y,q0.z,q0.w, q1.x,q1.y,q1.z,q1.w,
                      q2.x,q2.y,q2.z,q2.w, q3.x,q3.y,q3.z,q3.w};
      float s = acc[p];
      #pragma unroll
      for (int k = 0; k < 16; k++) s = fmaf(av[k], lv[k], s);
      acc[p] = s;
    }
    __syncthreads();
  }
  #pragma unroll
  for (int p = 0; p < 14; p++)
    outbuf[(b * 256 + tid) * 196 + y * 14 + p] = acc[p];
}

template<int CH>
__global__ __launch_bounds__(256) void bnstats_kernel(const float* __restrict__ buf,
    const float* __restrict__ g, const float* __restrict__ bb, float* __restrict__ ss)
{
  const int c = blockIdx.x, tid = threadIdx.x;
  float s = 0.f, s2 = 0.f;
  for (int e = tid; e < 32 * 196; e += 256) {
    int bi = e / 196, l = e - bi * 196;
    float v = buf[(bi * CH + c) * 196 + l];
    s += v; s2 = fmaf(v, v, s2);
  }
  #pragma unroll
  for (int off = 32; off; off >>= 1) { s += __shfl_down(s, off); s2 += __shfl_down(s2, off); }
  __shared__ float red[8];
  int w = tid >> 6;
  if ((tid & 63) == 0) { red[w] = s; red[4 + w] = s2; }
  __syncthreads();
  if (tid == 0) {
    float S  = red[0] + red[1] + red[2] + red[3];
    float S2 = red[4] + red[5] + red[6] + red[7];
    float mean = S * (1.f / 6272.f);
    float var  = S2 * (1.f / 6272.f) - mean * mean;
    float sc = g[c] * rsqrtf(var + EPSV);
    ss[c] = sc;
    ss[CH + c] = bb[c] - mean * sc;
  }
}

__global__ __launch_bounds__(256) void final_old_kernel(float* __restrict__ out3,
    const float* __restrict__ ss, const float* __restrict__ x)
{
  const int total = 32 * 1024 * 196;
  for (int idx = blockIdx.x * 256 + threadIdx.x; idx < total; idx += gridDim.x * 256) {
    int c = (idx / 196) & 1023;
    float v = out3[idx] * ss[c] + ss[1024 + c] + x[idx];
    out3[idx] = fmaxf(v, 0.f);
  }
}

// ============================================================================

extern "C" void kernel_launch(void* const* d_in, const int* in_sizes, int n_in,
                              void* d_out, int out_size, void* d_ws, size_t ws_size,
                              hipStream_t stream) {
  const float* x   = (const float*)d_in[0];
  const float* c1c = (const float*)d_in[1];
  const float* c1l = (const float*)d_in[2];
  const float* c1t = (const float*)d_in[3];
  const float* c2c = (const float*)d_in[4];
  const float* c2l = (const float*)d_in[5];
  const float* c2t = (const float*)d_in[6];
  const float* c3c = (const float*)d_in[7];
  const float* c3l = (const float*)d_in[8];
  const float* c3t = (const float*)d_in[9];
  const float* g1  = (const float*)d_in[10];
  const float* b1  = (const float*)d_in[11];
  const float* g2  = (const float*)d_in[12];
  const float* b2  = (const float*)d_in[13];
  const float* g3  = (const float*)d_in[14];
  const float* b3  = (const float*)d_in[15];

  float* ws = (float*)d_ws;
  const size_t FAST_NEED = 24255488ull * 4ull;   // ~97 MB (known-good layout)

  if (ws_size >= FAST_NEED) {
    // ---- fast MFMA path ----
    u16*   attnB = (u16*)ws;                         // 25,690,112 u16 (51 MB)
    float* partC = ws + 12845056;                    // 6,422,528 f = 4 x 1,605,632
    float* out1  = partC + 6422528;                  // 1,605,632 f
    float* out2  = out1 + 1605632;                   // 1,605,632 f
    bf16*  lutT1 = (bf16*)(out2 + 1605632);          // 1,048,576 u16
    bf16*  lutT2 = lutT1 + 1048576;
    bf16*  lutT3 = lutT2 + 1048576;
    float* acc1  = (float*)(lutT3 + 1048576);        // 512 f (S,S2 for bn1)
    float* acc2  = acc1 + 512;                       // 512 f
    float* acc3  = acc2 + 512;                       // 2048 f
    float* out3  = partC;
    const size_t PART_STRIDE = 1605632;              // 6272*256

    // fused attn1 (1024 blocks, full-image coalesced) + lut transposes (768)
    prep_kernel<<<1792, 256, 0, stream>>>(x, c1c, c1t, attnB,
                                          c1l, lutT1, c2l, lutT2, c3l, lutT3);

    // layer 1: 8-wave dbuf gemm (zeroes acc1), split-K4; bnpart sums + atomic stats
    gemm_kernel<4096, 2, 4, 128, 64><<<392, 512, 0, stream>>>(
        attnB, (const u16*)lutT1, partC, PART_STRIDE, acc1, 512, nullptr);
    bnpart_kernel<<<196, 256, 0, stream>>>(partC, out1, acc1);

    // layer 2 (attn2 v4: image x 16-cb blocks, grid 512; bn1 inline from acc1)
    attn2_kernel<<<512, 256, 0, stream>>>(out1, g1, b1, acc1, c2c, c2t, attnB);
    gemm_kernel<4096, 2, 4, 128, 64><<<392, 512, 0, stream>>>(
        attnB, (const u16*)lutT2, partC, PART_STRIDE, acc2, 2560, nullptr);
    //                                  ^ zeroes acc2 AND acc3 (contiguous)
    bnpart_kernel<<<196, 256, 0, stream>>>(partC, out2, acc2);

    // layer 3 (attn3 computes bn2 inline from acc2); gemm3 fuses bn3 stats
    attn3_kernel<<<392, 256, 0, stream>>>(out2, g2, b2, acc2, c3c, c3t, (bf16*)attnB);
    gemm_kernel<1024, 8, 1, 128, 64><<<392, 512, 0, stream>>>(
        attnB, (const u16*)lutT3, out3, 0, nullptr, 0, acc3);

    // final (bn3 inline from acc3)
    tfinal_kernel<<<512, 256, 0, stream>>>(out3, g3, b3, acc3, x, (float*)d_out);
  } else {
    // ---- fallback (round-2 proven path) ----
    float* out3 = (float*)d_out;
    float* out1 = ws;
    float* out2 = out1 + 32 * 256 * 196;
    float* ss1  = out2 + 32 * 256 * 196;
    float* ss2  = ss1 + 512;
    float* ss3  = ss2 + 512;

    amm1x1_kernel<1024, 256, false><<<448, 256, 0, stream>>>(x, nullptr, c1c, c1l, c1t, out1);
    bnstats_kernel<256><<<256, 256, 0, stream>>>(out1, g1, b1, ss1);
    amm3x3_kernel<<<448, 256, 0, stream>>>(out1, ss1, c2c, c2l, c2t, out2);
    bnstats_kernel<256><<<256, 256, 0, stream>>>(out2, g2, b2, ss2);
    amm1x1_kernel<256, 1024, true><<<448, 256, 0, stream>>>(out2, ss2, c3c, c3l, c3t, out3);
    bnstats_kernel<1024><<<1024, 256, 0, stream>>>(out3, g3, b3, ss3);
    final_old_kernel<<<2048, 256, 0, stream>>>(out3, ss3, x);
  }
}